// Round 6
// baseline (282.800 us; speedup 1.0000x reference)
//
#include <hip/hip_runtime.h>
#include <math.h>

#define S_ 4
#define R_ 2048
#define K_ 128
#define C_ 32
#define RES_ 128
#define G_ 128
#define H_ 128

typedef __bf16 bf16x8 __attribute__((ext_vector_type(8)));
typedef float f32x4 __attribute__((ext_vector_type(4)));
typedef float f32x2 __attribute__((ext_vector_type(2)));
typedef unsigned short u16x8 __attribute__((ext_vector_type(8)));

// ws layout (in floats)
#define CODET_OFF 0
#define CODET_SZ  (S_*3*RES_*RES_*C_/2)   // bf16: 3145728 floats
#define W1F_OFF   (CODET_OFF + CODET_SZ)
#define W1F_SZ    (128*96/2)              // 6144 floats
#define W2F_OFF   (W1F_OFF + W1F_SZ)
#define W2F_SZ    (128*128/2)             // 8192 floats
#define GB_OFF    (W2F_OFF + W2F_SZ)
#define GB_SZ     (S_*G_*G_*G_/32)        // 262144 uint words

// Unified LDS row stride (bf16 elements). 272 B row stride: 16B-multiple
// (aligned b128), consecutive rows offset by 4 banks -> worst 2-way = free.
// R2-R4 post-mortems: swizzle / packed f32x2 partials / launch-bound changes
// all induced scratch spill. k_fused MFMA body is FROZEN at the R1 shape
// (VGPR 64, scalar fmaf partials). R6 adds ONLY the render tail.
#define ROWP 136

__device__ __forceinline__ unsigned short f2bf(float x) {
  unsigned int u = __float_as_uint(x);
  unsigned int r = u + 0x7fffu + ((u >> 16) & 1u);
  return (unsigned short)(r >> 16);
}

// ---------------------------------------------------------------------------
// K0 (merged pre-pass):
//   blocks 0..767    : transpose+cvt code -> (S,3,RES,RES,C) bf16 (float4 loads)
//   blocks 768..1791 : density bitmask (coalesced loads + wave ballot)
//   blocks 1792..1807: weight fragments in MFMA B-operand lane order
// ---------------------------------------------------------------------------
__global__ __launch_bounds__(256) void k_pre(
    const float* __restrict__ src, unsigned short* __restrict__ dst,
    const int* __restrict__ dgrid, unsigned int* __restrict__ gbits,
    const float* __restrict__ W1, const float* __restrict__ W2,
    unsigned short* __restrict__ W1F, unsigned short* __restrict__ W2F) {
  __shared__ unsigned int tile[32 * 129];  // 16512 B, bf16-pair packed
  const int t = threadIdx.x;
  const int b = blockIdx.x;
  if (b < 768) {
    const int slab = b >> 6;          // 12 slabs = S*3 planes
    const int xy0 = (b & 63) << 8;    // 256 xy per block
    const float* sp = src + slab * (C_ * RES_ * RES_);
    unsigned short* dp = dst + slab * (RES_ * RES_ * C_);
    const int c = t >> 3, xg = t & 7;
#pragma unroll
    for (int j = 0; j < 8; ++j) {
      const int chunk = xg + 8 * j;  // 64 float4-chunks cover 256 xy
      const float4 v = *(const float4*)(sp + c * (RES_ * RES_) + xy0 + chunk * 4);
      const unsigned int lo = (unsigned int)f2bf(v.x) | ((unsigned int)f2bf(v.y) << 16);
      const unsigned int hi = (unsigned int)f2bf(v.z) | ((unsigned int)f2bf(v.w) << 16);
      tile[c * 129 + chunk * 2] = lo;
      tile[c * 129 + chunk * 2 + 1] = hi;
    }
    __syncthreads();
    const int xyb = t >> 2, chunk4 = t & 3;
#pragma unroll
    for (int j = 0; j < 4; ++j) {
      const int xy = 64 * j + xyb;
      const int idx = xy >> 1, sh = (xy & 1) * 16;
      u16x8 pk;
#pragma unroll
      for (int cc = 0; cc < 8; ++cc)
        pk[cc] = (unsigned short)(tile[(chunk4 * 8 + cc) * 129 + idx] >> sh);
      *(u16x8*)(dp + (xy0 + xy) * C_ + chunk4 * 8) = pk;
    }
  } else if (b < 1792) {
    const int base0 = (b - 768) * 8192;
    const int lane = t & 63;
#pragma unroll 4
    for (int j = 0; j < 32; ++j) {
      const int idx = base0 + j * 256 + t;
      const unsigned long long m = __ballot(dgrid[idx] > 0);
      if (lane == 0)
        gbits[idx >> 5] = (unsigned int)m;
      else if (lane == 32)
        gbits[idx >> 5] = (unsigned int)(m >> 32);
    }
  } else {
    const int slice = b - 1792;  // 0..15
    for (int i = slice * 256 + t; i < 128 * 96; i += 16 * 256) {
      const int j = i & 7, lane = (i >> 3) & 63, fi = i >> 9;
      const int nt = fi / 3, kt = fi - 3 * nt;
      const int k = kt * 32 + (lane >> 4) * 8 + j;
      const int n = nt * 16 + (lane & 15);
      W1F[i] = f2bf(W1[k * H_ + n]);
    }
    for (int i = slice * 256 + t; i < 128 * 128; i += 16 * 256) {
      const int j = i & 7, lane = (i >> 3) & 63, fi = i >> 9;
      const int nt = fi >> 2, kt = fi & 3;
      const int k = kt * 32 + (lane >> 4) * 8 + j;
      const int n = nt * 16 + (lane & 15);
      W2F[i] = f2bf(W2[k * H_ + n]);
    }
  }
}

// ---------------------------------------------------------------------------
__device__ __forceinline__ void near_far(float ox, float oy, float oz,
                                         float dx, float dy, float dz,
                                         float& nearv, float& farv) {
  float ddx = fabsf(dx) < 1e-9f ? 1e-9f : dx;
  float ddy = fabsf(dy) < 1e-9f ? 1e-9f : dy;
  float ddz = fabsf(dz) < 1e-9f ? 1e-9f : dz;
  float ix = 1.f / ddx, iy = 1.f / ddy, iz = 1.f / ddz;
  float t1x = (-1.f - ox) * ix, t2x = (1.f - ox) * ix;
  float t1y = (-1.f - oy) * iy, t2y = (1.f - oy) * iy;
  float t1z = (-1.f - oz) * iz, t2z = (1.f - oz) * iz;
  float mnx = fminf(t1x, t2x), mxx = fmaxf(t1x, t2x);
  float mny = fminf(t1y, t2y), mxy = fmaxf(t1y, t2y);
  float mnz = fminf(t1z, t2z), mxz = fmaxf(t1z, t2z);
  nearv = fmaxf(fmaxf(fmaxf(mnx, mny), mnz), 0.2f);
  farv = fmaxf(fminf(fminf(mxx, mxy), mxz), nearv);
}

// pair-halving butterfly over the 16 ln-lanes: 16 values -> 1 per lane
__device__ __forceinline__ float reduce16(const float (&part)[4][4], const int ln) {
  float v16[16];
#pragma unroll
  for (int rr = 0; rr < 4; ++rr)
#pragma unroll
    for (int qq = 0; qq < 4; ++qq) v16[rr * 4 + qq] = part[rr][qq];
  float v8[8];
#pragma unroll
  for (int j = 0; j < 8; ++j) {
    const float a = v16[2 * j], c = v16[2 * j + 1];
    const float send = (ln & 1) ? a : c;
    const float keep = (ln & 1) ? c : a;
    v8[j] = keep + __shfl_xor(send, 1);
  }
  float v4a[4];
#pragma unroll
  for (int j = 0; j < 4; ++j) {
    const float a = v8[2 * j], c = v8[2 * j + 1];
    const float send = (ln & 2) ? a : c;
    const float keep = (ln & 2) ? c : a;
    v4a[j] = keep + __shfl_xor(send, 2);
  }
  float v2a[2];
#pragma unroll
  for (int j = 0; j < 2; ++j) {
    const float a = v4a[2 * j], c = v4a[2 * j + 1];
    const float send = (ln & 4) ? a : c;
    const float keep = (ln & 4) ? c : a;
    v2a[j] = keep + __shfl_xor(send, 4);
  }
  const float a = v2a[0], c = v2a[1];
  const float send = (ln & 8) ? a : c;
  const float keep = (ln & 8) ? c : a;
  return keep + __shfl_xor(send, 8);
}

// ---------------------------------------------------------------------------
// K1: fused sampling + MLP + render.
// Body = EXACT r11/r5 code (181 us, VGPR 64, scalar fmaf partials).
// r16 adds ONLY the render tail: stage (sigma,rgb) into the smem alias
// (all waves have finished reading their own h1 rows by then), one barrier,
// wave 0 reloads ray data (L1-hot) and runs the k_render scan from LDS.
// Deletes k_render, the 16 MB sr write + 16 MB sr read, one launch.
// ---------------------------------------------------------------------------
__global__ __launch_bounds__(256, 4) void k_fused(
    const float* __restrict__ rays_o, const float* __restrict__ rays_d,
    const unsigned short* __restrict__ codeT, const unsigned int* __restrict__ gbits,
    const unsigned short* __restrict__ W1F, const float* __restrict__ b1,
    const unsigned short* __restrict__ W2F, const float* __restrict__ b2,
    const float* __restrict__ W3, const float* __restrict__ b3,
    float* __restrict__ out) {
  __shared__ __align__(16) unsigned short smem[128 * ROWP];  // 34816 B (fA & h1 & rgbs alias)
  unsigned short* fA = smem;   // feats: rows [p][0..96)
  unsigned short* h1s = smem;  // h1:    rows [m][0..128)
  float* rgbs = (float*)smem;  // render staging: 128 x float4 (2 KB), written last

  const int t = threadIdx.x;
  const int w = t >> 6, lane = t & 63;
  const int quad = lane >> 4, ln = lane & 15;
  const int p = t >> 1, q = t & 1;  // sampling role: point p (0..127), channel-half q
  const int ray = blockIdx.x;       // 8192 rays, one per block
  const int s = ray >> 11;

  const float* ob = rays_o + ray * 3;
  const float* db = rays_d + ray * 3;
  const float ox = ob[0], oy = ob[1], oz = ob[2];
  const float dx = db[0], dy = db[1], dz = db[2];
  float nearv, farv;
  near_far(ox, oy, oz, dx, dy, dz, nearv, farv);

  // ---- EARLY occupancy-grid loads for this lane's two epilogue points ----
  const int q_s = ln & 3, rr_s = ln >> 2;
  const int m_o0 = 32 * w + quad * 4 + rr_s;
  const int m_o1 = m_o0 + 16;
  unsigned int occw0, occw1;
  int occb0, occb1;
  {
    const float zm = nearv + (farv - nearv) * ((m_o0 + 0.5f) * (1.0f / K_));
    const float pxm = fminf(fmaxf(ox + dx * zm, -1.f), 1.f);
    const float pym = fminf(fmaxf(oy + dy * zm, -1.f), 1.f);
    const float pzm = fminf(fmaxf(oz + dz * zm, -1.f), 1.f);
    const int i0 = min((int)((pxm + 1.f) * 64.f), G_ - 1);
    const int i1 = min((int)((pym + 1.f) * 64.f), G_ - 1);
    const int i2 = min((int)((pzm + 1.f) * 64.f), G_ - 1);
    const int bidx = ((s * G_ + i0) * G_ + i1) * G_ + i2;
    occw0 = gbits[bidx >> 5];
    occb0 = bidx & 31;
  }
  {
    const float zm = nearv + (farv - nearv) * ((m_o1 + 0.5f) * (1.0f / K_));
    const float pxm = fminf(fmaxf(ox + dx * zm, -1.f), 1.f);
    const float pym = fminf(fmaxf(oy + dy * zm, -1.f), 1.f);
    const float pzm = fminf(fmaxf(oz + dz * zm, -1.f), 1.f);
    const int i0 = min((int)((pxm + 1.f) * 64.f), G_ - 1);
    const int i1 = min((int)((pym + 1.f) * 64.f), G_ - 1);
    const int i2 = min((int)((pzm + 1.f) * 64.f), G_ - 1);
    const int bidx = ((s * G_ + i0) * G_ + i1) * G_ + i2;
    occw1 = gbits[bidx >> 5];
    occb1 = bidx & 31;
  }

  // ---- this thread's sample point ----
  const float zs = nearv + (farv - nearv) * ((p + 0.5f) * (1.0f / K_));
  const float px = fminf(fmaxf(ox + dx * zs, -1.f), 1.f);
  const float py = fminf(fmaxf(oy + dy * zs, -1.f), 1.f);
  const float pz = fminf(fmaxf(oz + dz * zs, -1.f), 1.f);

  // ---- per-plane bilinear setup ----
  float w00a, w01a, w10a, w11a, w00b, w01b, w10b, w11b, w00c, w01c, w10c, w11c;
  int off0, off1, off2;
  {
    float fx = (px + 1.f) * 0.5f * 127.f, fy = (py + 1.f) * 0.5f * 127.f;
    int xi = min((int)fx, RES_ - 2), yi = min((int)fy, RES_ - 2);
    float wx = fx - (float)xi, wy = fy - (float)yi;
    w00a = (1.f - wx) * (1.f - wy); w01a = wx * (1.f - wy);
    w10a = (1.f - wx) * wy;         w11a = wx * wy;
    off0 = ((s * 3 + 0) * (RES_ * RES_) + yi * RES_ + xi) * C_;
  }
  {
    float fx = (px + 1.f) * 0.5f * 127.f, fy = (pz + 1.f) * 0.5f * 127.f;
    int xi = min((int)fx, RES_ - 2), yi = min((int)fy, RES_ - 2);
    float wx = fx - (float)xi, wy = fy - (float)yi;
    w00b = (1.f - wx) * (1.f - wy); w01b = wx * (1.f - wy);
    w10b = (1.f - wx) * wy;         w11b = wx * wy;
    off1 = ((s * 3 + 1) * (RES_ * RES_) + yi * RES_ + xi) * C_;
  }
  {
    float fx = (py + 1.f) * 0.5f * 127.f, fy = (pz + 1.f) * 0.5f * 127.f;
    int xi = min((int)fx, RES_ - 2), yi = min((int)fy, RES_ - 2);
    float wx = fx - (float)xi, wy = fy - (float)yi;
    w00c = (1.f - wx) * (1.f - wy); w01c = wx * (1.f - wy);
    w10c = (1.f - wx) * wy;         w11c = wx * wy;
    off2 = ((s * 3 + 2) * (RES_ * RES_) + yi * RES_ + xi) * C_;
  }

  // ---- gather: channels [48q,48q+48) as 6 chunks of 8; f32x2 packed math,
  //      bf16 repack via v_perm truncation (RTZ) ----
#pragma unroll
  for (int u = 0; u < 6; ++u) {
    const int f = 48 * q + 8 * u;  // chunk never crosses a plane boundary
    const int pl = f >> 5;
    const int c = f & 31;
    const int off = (pl == 0) ? off0 : ((pl == 1) ? off1 : off2);
    const float W00 = (pl == 0) ? w00a : ((pl == 1) ? w00b : w00c);
    const float W01 = (pl == 0) ? w01a : ((pl == 1) ? w01b : w01c);
    const float W10 = (pl == 0) ? w10a : ((pl == 1) ? w10b : w10c);
    const float W11 = (pl == 0) ? w11a : ((pl == 1) ? w11b : w11c);
    const unsigned short* bp = codeT + off + c;
    const uint4 A = *(const uint4*)(bp);
    const uint4 B = *(const uint4*)(bp + C_);
    const uint4 Cv = *(const uint4*)(bp + RES_ * C_);
    const uint4 D = *(const uint4*)(bp + RES_ * C_ + C_);
    const unsigned int aw[4] = {A.x, A.y, A.z, A.w};
    const unsigned int bw[4] = {B.x, B.y, B.z, B.w};
    const unsigned int cw[4] = {Cv.x, Cv.y, Cv.z, Cv.w};
    const unsigned int dw[4] = {D.x, D.y, D.z, D.w};
    const f32x2 W00v = {W00, W00}, W01v = {W01, W01}, W10v = {W10, W10}, W11v = {W11, W11};
    unsigned int ow[4];
#pragma unroll
    for (int e2 = 0; e2 < 4; ++e2) {
      const f32x2 va = {__uint_as_float(aw[e2] << 16), __uint_as_float(aw[e2] & 0xffff0000u)};
      const f32x2 vb = {__uint_as_float(bw[e2] << 16), __uint_as_float(bw[e2] & 0xffff0000u)};
      const f32x2 vc = {__uint_as_float(cw[e2] << 16), __uint_as_float(cw[e2] & 0xffff0000u)};
      const f32x2 vd = {__uint_as_float(dw[e2] << 16), __uint_as_float(dw[e2] & 0xffff0000u)};
      const f32x2 fv = W00v * va + W01v * vb + W10v * vc + W11v * vd;
      ow[e2] = __builtin_amdgcn_perm(__float_as_uint(fv[1]), __float_as_uint(fv[0]),
                                     0x07060302u);
    }
    *(uint4*)(fA + p * ROWP + f) = make_uint4(ow[0], ow[1], ow[2], ow[3]);
  }
  // wave-local LDS (wave w: rows [32w,32w+32)) -> no barrier.

  const int rowA = 32 * w + ln;
  const int rowB = rowA + 16;

  // ---- layer 1: feats(128x96) @ W1^T -> h1 bf16; two m-tiles per wave so
  //      every B-fragment is used twice. All 6 A-frags loaded BEFORE any h1
  //      write: fA region then dead -> safe alias. ----
  {
    bf16x8 aA[3], aB[3];
#pragma unroll
    for (int kt = 0; kt < 3; ++kt) {
      aA[kt] = *(const bf16x8*)(fA + rowA * ROWP + kt * 32 + quad * 8);
      aB[kt] = *(const bf16x8*)(fA + rowB * ROWP + kt * 32 + quad * 8);
    }
#pragma unroll
    for (int nt = 0; nt < 8; ++nt) {
      const bf16x8 b0 = *(const bf16x8*)(W1F + ((nt * 3 + 0) * 64 + lane) * 8);
      const bf16x8 b1v = *(const bf16x8*)(W1F + ((nt * 3 + 1) * 64 + lane) * 8);
      const bf16x8 b2v = *(const bf16x8*)(W1F + ((nt * 3 + 2) * 64 + lane) * 8);
      f32x4 accA = {0.f, 0.f, 0.f, 0.f};
      f32x4 accB = {0.f, 0.f, 0.f, 0.f};
      accA = __builtin_amdgcn_mfma_f32_16x16x32_bf16(aA[0], b0, accA, 0, 0, 0);
      accB = __builtin_amdgcn_mfma_f32_16x16x32_bf16(aB[0], b0, accB, 0, 0, 0);
      accA = __builtin_amdgcn_mfma_f32_16x16x32_bf16(aA[1], b1v, accA, 0, 0, 0);
      accB = __builtin_amdgcn_mfma_f32_16x16x32_bf16(aB[1], b1v, accB, 0, 0, 0);
      accA = __builtin_amdgcn_mfma_f32_16x16x32_bf16(aA[2], b2v, accA, 0, 0, 0);
      accB = __builtin_amdgcn_mfma_f32_16x16x32_bf16(aB[2], b2v, accB, 0, 0, 0);
      const int n = nt * 16 + ln;
      const float bias = b1[n];
#pragma unroll
      for (int rr = 0; rr < 4; ++rr) {
        const int mA = 32 * w + quad * 4 + rr;
        const float vA = fmaxf(accA[rr] + bias, 0.f);
        h1s[mA * ROWP + n] = (unsigned short)(__float_as_uint(vA) >> 16);
        const float vB = fmaxf(accB[rr] + bias, 0.f);
        h1s[(mA + 16) * ROWP + n] = (unsigned short)(__float_as_uint(vB) >> 16);
      }
    }
  }

  // ---- layer 2 + layer 3 partials, per-nt epilogue keeps acc live = 8 ----
  float part0[4][4], part1[4][4];
#pragma unroll
  for (int rr = 0; rr < 4; ++rr)
#pragma unroll
    for (int qq = 0; qq < 4; ++qq) {
      part0[rr][qq] = 0.f;
      part1[rr][qq] = 0.f;
    }
  {
    bf16x8 aA[4], aB[4];
#pragma unroll
    for (int kt = 0; kt < 4; ++kt) {
      aA[kt] = *(const bf16x8*)(h1s + rowA * ROWP + kt * 32 + quad * 8);
      aB[kt] = *(const bf16x8*)(h1s + rowB * ROWP + kt * 32 + quad * 8);
    }
#pragma unroll
    for (int nt = 0; nt < 8; ++nt) {
      const bf16x8 b0 = *(const bf16x8*)(W2F + ((nt * 4 + 0) * 64 + lane) * 8);
      const bf16x8 b1v = *(const bf16x8*)(W2F + ((nt * 4 + 1) * 64 + lane) * 8);
      const bf16x8 b2v = *(const bf16x8*)(W2F + ((nt * 4 + 2) * 64 + lane) * 8);
      const bf16x8 b3v = *(const bf16x8*)(W2F + ((nt * 4 + 3) * 64 + lane) * 8);
      f32x4 accA = {0.f, 0.f, 0.f, 0.f};
      f32x4 accB = {0.f, 0.f, 0.f, 0.f};
      accA = __builtin_amdgcn_mfma_f32_16x16x32_bf16(aA[0], b0, accA, 0, 0, 0);
      accB = __builtin_amdgcn_mfma_f32_16x16x32_bf16(aB[0], b0, accB, 0, 0, 0);
      accA = __builtin_amdgcn_mfma_f32_16x16x32_bf16(aA[1], b1v, accA, 0, 0, 0);
      accB = __builtin_amdgcn_mfma_f32_16x16x32_bf16(aB[1], b1v, accB, 0, 0, 0);
      accA = __builtin_amdgcn_mfma_f32_16x16x32_bf16(aA[2], b2v, accA, 0, 0, 0);
      accB = __builtin_amdgcn_mfma_f32_16x16x32_bf16(aB[2], b2v, accB, 0, 0, 0);
      accA = __builtin_amdgcn_mfma_f32_16x16x32_bf16(aA[3], b3v, accA, 0, 0, 0);
      accB = __builtin_amdgcn_mfma_f32_16x16x32_bf16(aB[3], b3v, accB, 0, 0, 0);
      const int n = nt * 16 + ln;
      const float b2n = b2[n];
      const float4 w3v = *(const float4*)(W3 + n * 4);
#pragma unroll
      for (int rr = 0; rr < 4; ++rr) {
        const float hA = fmaxf(accA[rr] + b2n, 0.f);
        part0[rr][0] = fmaf(hA, w3v.x, part0[rr][0]);
        part0[rr][1] = fmaf(hA, w3v.y, part0[rr][1]);
        part0[rr][2] = fmaf(hA, w3v.z, part0[rr][2]);
        part0[rr][3] = fmaf(hA, w3v.w, part0[rr][3]);
        const float hB = fmaxf(accB[rr] + b2n, 0.f);
        part1[rr][0] = fmaf(hB, w3v.x, part1[rr][0]);
        part1[rr][1] = fmaf(hB, w3v.y, part1[rr][1]);
        part1[rr][2] = fmaf(hB, w3v.z, part1[rr][2]);
        part1[rr][3] = fmaf(hB, w3v.w, part1[rr][3]);
      }
    }
  }

  // ---- reductions: lane -> (m = m_o0/m_o1, q = q_s); stage into LDS alias.
  //      Safe barrier-free: this wave only overwrites bytes in rows [0,8) of
  //      the h1 region, and every wave has finished its h1 reads above; the
  //      cross-wave read happens only after the barrier below. ----
  const float bq = b3[q_s];
  {
    const float val = reduce16(part0, ln) + bq;
    float outv;
    if (q_s == 0) {
      const int occ = (occw0 >> occb0) & 1;
      const float sp = val > 20.f ? val : log1pf(expf(val));
      outv = occ ? sp : 0.f;
    } else {
      outv = 1.f / (1.f + expf(-val));
    }
    rgbs[m_o0 * 4 + q_s] = outv;
  }
  {
    const float val = reduce16(part1, ln) + bq;
    float outv;
    if (q_s == 0) {
      const int occ = (occw1 >> occb1) & 1;
      const float sp = val > 20.f ? val : log1pf(expf(val));
      outv = occ ? sp : 0.f;
    } else {
      outv = 1.f / (1.f + expf(-val));
    }
    rgbs[m_o1 * 4 + q_s] = outv;
  }

  // ---- fused volume render: wave 0 runs the scan from LDS ----
  __syncthreads();
  if (w == 0) {
    // reload ray data (L1-hot) instead of keeping it live across the body
    const float ox2 = ob[0], oy2 = ob[1], oz2 = ob[2];
    const float dx2 = db[0], dy2 = db[1], dz2 = db[2];
    float nv, fv;
    near_far(ox2, oy2, oz2, dx2, dy2, dz2, nv, fv);
    const float delta = (fv - nv) * (1.0f / K_);
    const int k0 = lane * 2;
    const float4 A = *(const float4*)&rgbs[k0 * 4];
    const float4 B = *(const float4*)&rgbs[k0 * 4 + 4];
    const float tau0 = A.x * delta, tau1 = B.x * delta;
    const float local = tau0 + tau1;
    float scan = local;
#pragma unroll
    for (int off = 1; off < 64; off <<= 1) {
      const float vsh = __shfl_up(scan, off);
      if (lane >= off) scan += vsh;
    }
    const float pre = scan - local;
    const float T0 = expf(-pre);
    const float T1 = expf(-(pre + tau0));
    const float a0 = 1.f - expf(-tau0);
    const float a1 = 1.f - expf(-tau1);
    const float w0 = (T0 > 1e-4f) ? a0 * T0 : 0.f;
    const float w1 = (T1 > 1e-4f) ? a1 * T1 : 0.f;
    const float z0 = nv + (fv - nv) * ((k0 + 0.5f) * (1.f / K_));
    const float z1 = nv + (fv - nv) * ((k0 + 1.5f) * (1.f / K_));

    float sw = w0 + w1;
    float sd = w0 * z0 + w1 * z1;
    float sred = w0 * A.y + w1 * B.y;
    float sgrn = w0 * A.z + w1 * B.z;
    float sblu = w0 * A.w + w1 * B.w;
#pragma unroll
    for (int mk = 32; mk >= 1; mk >>= 1) {
      sw += __shfl_xor(sw, mk);
      sd += __shfl_xor(sd, mk);
      sred += __shfl_xor(sred, mk);
      sgrn += __shfl_xor(sgrn, mk);
      sblu += __shfl_xor(sblu, mk);
    }
    if (lane == 0) {
      out[ray] = sw;
      out[S_ * R_ + ray] = sd;
      out[2 * S_ * R_ + ray * 3 + 0] = sred;
      out[2 * S_ * R_ + ray * 3 + 1] = sgrn;
      out[2 * S_ * R_ + ray * 3 + 2] = sblu;
    }
  }
}

// ---------------------------------------------------------------------------
extern "C" void kernel_launch(void* const* d_in, const int* in_sizes, int n_in,
                              void* d_out, int out_size, void* d_ws, size_t ws_size,
                              hipStream_t stream) {
  const float* rays_o = (const float*)d_in[0];
  const float* rays_d = (const float*)d_in[1];
  const float* code = (const float*)d_in[2];
  const int* dgrid = (const int*)d_in[3];
  const float* W1 = (const float*)d_in[5];
  const float* b1 = (const float*)d_in[6];
  const float* W2 = (const float*)d_in[7];
  const float* b2 = (const float*)d_in[8];
  const float* W3 = (const float*)d_in[9];
  const float* b3 = (const float*)d_in[10];

  float* ws = (float*)d_ws;
  unsigned short* codeT = (unsigned short*)(ws + CODET_OFF);
  unsigned short* W1F = (unsigned short*)(ws + W1F_OFF);
  unsigned short* W2F = (unsigned short*)(ws + W2F_OFF);
  unsigned int* gbits = (unsigned int*)(ws + GB_OFF);

  hipLaunchKernelGGL(k_pre, dim3(1808), dim3(256), 0, stream,
                     code, codeT, dgrid, gbits, W1, W2, W1F, W2F);
  hipLaunchKernelGGL(k_fused, dim3(S_ * R_), dim3(256), 0, stream,
                     rays_o, rays_d, codeT, gbits, W1F, b1, W2F, b2, W3, b3,
                     (float*)d_out);
}

// Round 9
// 278.884 us; speedup vs baseline: 1.0140x; 1.0140x over previous
//
#include <hip/hip_runtime.h>
#include <math.h>

#define S_ 4
#define R_ 2048
#define K_ 128
#define C_ 32
#define RES_ 128
#define G_ 128
#define H_ 128

typedef __bf16 bf16x8 __attribute__((ext_vector_type(8)));
typedef float f32x4 __attribute__((ext_vector_type(4)));
typedef float f32x2 __attribute__((ext_vector_type(2)));
typedef unsigned short u16x8 __attribute__((ext_vector_type(8)));

// ws layout (in floats)
#define CODET_OFF 0
#define CODET_SZ  (S_*3*RES_*RES_*C_/2)   // bf16: 3145728 floats
#define W1F_OFF   (CODET_OFF + CODET_SZ)
#define W1F_SZ    (128*96/2)              // 6144 floats
#define W2F_OFF   (W1F_OFF + W1F_SZ)
#define W2F_SZ    (128*128/2)             // 8192 floats
#define GB_OFF    (W2F_OFF + W2F_SZ)
#define GB_SZ     (S_*G_*G_*G_/32)        // 262144 uint words
#define W3F_OFF   (GB_OFF + GB_SZ)
#define W3F_SZ    (4*64*8/2)              // 1024 floats (2048 bf16)
#define SR_OFF    (W3F_OFF + W3F_SZ)      // 4194304 floats

// Unified LDS row stride (bf16 elements). 272 B row stride: 16B-multiple
// (aligned b128), consecutive rows offset by 4 banks -> worst 2-way = free.
// Frozen-regime notes (R2-R4,R6 post-mortems): launch-bound changes, LDS
// swizzle, packed f32x2 partials, and the fused-render tail all regressed
// (spill storms or alias race). Render stays split; MFMA body stays at the
// R1 shape. R7/R8 change ONLY the layer-3 epilogue: scalar fmaf+reduce16
// (~400 VALU ops/thread) -> 8 MFMAs vs pre-fragmented W3F + 8-shuffle
// redistribution. R8: clamped the W3F-prep read address (W3[k*4+(n&3)]) —
// the R7 form's guarded-but-speculatable W3[k*4+n] could read 11 floats OOB
// if hipcc converts the ternary to load+cndmask; suspected container-killer.
#define ROWP 136

__device__ __forceinline__ unsigned short f2bf(float x) {
  unsigned int u = __float_as_uint(x);
  unsigned int r = u + 0x7fffu + ((u >> 16) & 1u);
  return (unsigned short)(r >> 16);
}

// ---------------------------------------------------------------------------
// K0 (merged pre-pass):
//   blocks 0..767    : transpose+cvt code -> (S,3,RES,RES,C) bf16 (float4 loads)
//   blocks 768..1791 : density bitmask (coalesced loads + wave ballot)
//   blocks 1792..1807: weight fragments (W1F/W2F/W3F) in MFMA B-operand order
// ---------------------------------------------------------------------------
__global__ __launch_bounds__(256) void k_pre(
    const float* __restrict__ src, unsigned short* __restrict__ dst,
    const int* __restrict__ dgrid, unsigned int* __restrict__ gbits,
    const float* __restrict__ W1, const float* __restrict__ W2,
    const float* __restrict__ W3,
    unsigned short* __restrict__ W1F, unsigned short* __restrict__ W2F,
    unsigned short* __restrict__ W3F) {
  __shared__ unsigned int tile[32 * 129];  // 16512 B, bf16-pair packed
  const int t = threadIdx.x;
  const int b = blockIdx.x;
  if (b < 768) {
    const int slab = b >> 6;          // 12 slabs = S*3 planes
    const int xy0 = (b & 63) << 8;    // 256 xy per block
    const float* sp = src + slab * (C_ * RES_ * RES_);
    unsigned short* dp = dst + slab * (RES_ * RES_ * C_);
    const int c = t >> 3, xg = t & 7;
#pragma unroll
    for (int j = 0; j < 8; ++j) {
      const int chunk = xg + 8 * j;  // 64 float4-chunks cover 256 xy
      const float4 v = *(const float4*)(sp + c * (RES_ * RES_) + xy0 + chunk * 4);
      const unsigned int lo = (unsigned int)f2bf(v.x) | ((unsigned int)f2bf(v.y) << 16);
      const unsigned int hi = (unsigned int)f2bf(v.z) | ((unsigned int)f2bf(v.w) << 16);
      tile[c * 129 + chunk * 2] = lo;
      tile[c * 129 + chunk * 2 + 1] = hi;
    }
    __syncthreads();
    const int xyb = t >> 2, chunk4 = t & 3;
#pragma unroll
    for (int j = 0; j < 4; ++j) {
      const int xy = 64 * j + xyb;
      const int idx = xy >> 1, sh = (xy & 1) * 16;
      u16x8 pk;
#pragma unroll
      for (int cc = 0; cc < 8; ++cc)
        pk[cc] = (unsigned short)(tile[(chunk4 * 8 + cc) * 129 + idx] >> sh);
      *(u16x8*)(dp + (xy0 + xy) * C_ + chunk4 * 8) = pk;
    }
  } else if (b < 1792) {
    const int base0 = (b - 768) * 8192;
    const int lane = t & 63;
#pragma unroll 4
    for (int j = 0; j < 32; ++j) {
      const int idx = base0 + j * 256 + t;
      const unsigned long long m = __ballot(dgrid[idx] > 0);
      if (lane == 0)
        gbits[idx >> 5] = (unsigned int)m;
      else if (lane == 32)
        gbits[idx >> 5] = (unsigned int)(m >> 32);
    }
  } else {
    const int slice = b - 1792;  // 0..15
    for (int i = slice * 256 + t; i < 128 * 96; i += 16 * 256) {
      const int j = i & 7, lane = (i >> 3) & 63, fi = i >> 9;
      const int nt = fi / 3, kt = fi - 3 * nt;
      const int k = kt * 32 + (lane >> 4) * 8 + j;
      const int n = nt * 16 + (lane & 15);
      W1F[i] = f2bf(W1[k * H_ + n]);
    }
    for (int i = slice * 256 + t; i < 128 * 128; i += 16 * 256) {
      const int j = i & 7, lane = (i >> 3) & 63, fi = i >> 9;
      const int nt = fi >> 2, kt = fi & 3;
      const int k = kt * 32 + (lane >> 4) * 8 + j;
      const int n = nt * 16 + (lane & 15);
      W2F[i] = f2bf(W2[k * H_ + n]);
    }
    // W3F: 4 k-frags of (128 x 4->16-padded); slices 0..7 cover i<2048.
    // Address clamped to n&3 (always in-bounds, max W3[511]); value selected
    // to 0 for n>=4. No OOB even under speculative load transforms.
    for (int i = slice * 256 + t; i < 4 * 64 * 8; i += 16 * 256) {
      const int j = i & 7, lane = (i >> 3) & 63, kt = i >> 9;
      const int k = kt * 32 + (lane >> 4) * 8 + j;
      const int n = lane & 15;
      const unsigned short v = f2bf(W3[k * 4 + (n & 3)]);
      W3F[i] = (n < 4) ? v : (unsigned short)0;
    }
  }
}

// ---------------------------------------------------------------------------
__device__ __forceinline__ void near_far(float ox, float oy, float oz,
                                         float dx, float dy, float dz,
                                         float& nearv, float& farv) {
  float ddx = fabsf(dx) < 1e-9f ? 1e-9f : dx;
  float ddy = fabsf(dy) < 1e-9f ? 1e-9f : dy;
  float ddz = fabsf(dz) < 1e-9f ? 1e-9f : dz;
  float ix = 1.f / ddx, iy = 1.f / ddy, iz = 1.f / ddz;
  float t1x = (-1.f - ox) * ix, t2x = (1.f - ox) * ix;
  float t1y = (-1.f - oy) * iy, t2y = (1.f - oy) * iy;
  float t1z = (-1.f - oz) * iz, t2z = (1.f - oz) * iz;
  float mnx = fminf(t1x, t2x), mxx = fmaxf(t1x, t2x);
  float mny = fminf(t1y, t2y), mxy = fmaxf(t1y, t2y);
  float mnz = fminf(t1z, t2z), mxz = fmaxf(t1z, t2z);
  nearv = fmaxf(fmaxf(fmaxf(mnx, mny), mnz), 0.2f);
  farv = fmaxf(fminf(fminf(mxx, mxy), mxz), nearv);
}

// ---------------------------------------------------------------------------
// K1: fused sampling + MLP.
// Body through layer 2 = EXACT r11/r5 code (181 us, VGPR 64, no spill).
// Layer 3 via MFMA: layer-2 epilogue stores h2 (bf16, RTZ trunc like h1)
// into the SAME wave-local rows (h1 dead after the layer-2 A-frag loads ->
// safe alias, same proven pattern as fA->h1). Then 8 MFMAs vs W3F and an
// 8-shuffle redistribution back to the old (q_s, rr_s) lane mapping so the
// occ/softplus/sigmoid/store tail is unchanged.
// Replaces 256 fmaf + 2x reduce16 (~400 VALU ops + 30 shfl per thread).
// ---------------------------------------------------------------------------
__global__ __launch_bounds__(256, 4) void k_fused(
    const float* __restrict__ rays_o, const float* __restrict__ rays_d,
    const unsigned short* __restrict__ codeT, const unsigned int* __restrict__ gbits,
    const unsigned short* __restrict__ W1F, const float* __restrict__ b1,
    const unsigned short* __restrict__ W2F, const float* __restrict__ b2,
    const unsigned short* __restrict__ W3F, const float* __restrict__ b3,
    float* __restrict__ sr) {
  __shared__ __align__(16) unsigned short smem[128 * ROWP];  // 34816 B (fA & h1 & h2 alias)
  unsigned short* fA = smem;   // feats: rows [p][0..96)
  unsigned short* h1s = smem;  // h1 then h2: rows [m][0..128)

  const int t = threadIdx.x;
  const int w = t >> 6, lane = t & 63;
  const int quad = lane >> 4, ln = lane & 15;
  const int p = t >> 1, q = t & 1;  // sampling role: point p (0..127), channel-half q
  const int ray = blockIdx.x;       // 8192 rays, one per block
  const int s = ray >> 11;
  const int pG0 = ray * K_;

  const float* ob = rays_o + ray * 3;
  const float* db = rays_d + ray * 3;
  const float ox = ob[0], oy = ob[1], oz = ob[2];
  const float dx = db[0], dy = db[1], dz = db[2];
  float nearv, farv;
  near_far(ox, oy, oz, dx, dy, dz, nearv, farv);

  // ---- EARLY occupancy-grid loads for this lane's two epilogue points ----
  const int q_s = ln & 3, rr_s = ln >> 2;
  const int m_o0 = 32 * w + quad * 4 + rr_s;
  const int m_o1 = m_o0 + 16;
  unsigned int occw0, occw1;
  int occb0, occb1;
  {
    const float zm = nearv + (farv - nearv) * ((m_o0 + 0.5f) * (1.0f / K_));
    const float pxm = fminf(fmaxf(ox + dx * zm, -1.f), 1.f);
    const float pym = fminf(fmaxf(oy + dy * zm, -1.f), 1.f);
    const float pzm = fminf(fmaxf(oz + dz * zm, -1.f), 1.f);
    const int i0 = min((int)((pxm + 1.f) * 64.f), G_ - 1);
    const int i1 = min((int)((pym + 1.f) * 64.f), G_ - 1);
    const int i2 = min((int)((pzm + 1.f) * 64.f), G_ - 1);
    const int bidx = ((s * G_ + i0) * G_ + i1) * G_ + i2;
    occw0 = gbits[bidx >> 5];
    occb0 = bidx & 31;
  }
  {
    const float zm = nearv + (farv - nearv) * ((m_o1 + 0.5f) * (1.0f / K_));
    const float pxm = fminf(fmaxf(ox + dx * zm, -1.f), 1.f);
    const float pym = fminf(fmaxf(oy + dy * zm, -1.f), 1.f);
    const float pzm = fminf(fmaxf(oz + dz * zm, -1.f), 1.f);
    const int i0 = min((int)((pxm + 1.f) * 64.f), G_ - 1);
    const int i1 = min((int)((pym + 1.f) * 64.f), G_ - 1);
    const int i2 = min((int)((pzm + 1.f) * 64.f), G_ - 1);
    const int bidx = ((s * G_ + i0) * G_ + i1) * G_ + i2;
    occw1 = gbits[bidx >> 5];
    occb1 = bidx & 31;
  }

  // ---- this thread's sample point ----
  const float zs = nearv + (farv - nearv) * ((p + 0.5f) * (1.0f / K_));
  const float px = fminf(fmaxf(ox + dx * zs, -1.f), 1.f);
  const float py = fminf(fmaxf(oy + dy * zs, -1.f), 1.f);
  const float pz = fminf(fmaxf(oz + dz * zs, -1.f), 1.f);

  // ---- per-plane bilinear setup ----
  float w00a, w01a, w10a, w11a, w00b, w01b, w10b, w11b, w00c, w01c, w10c, w11c;
  int off0, off1, off2;
  {
    float fx = (px + 1.f) * 0.5f * 127.f, fy = (py + 1.f) * 0.5f * 127.f;
    int xi = min((int)fx, RES_ - 2), yi = min((int)fy, RES_ - 2);
    float wx = fx - (float)xi, wy = fy - (float)yi;
    w00a = (1.f - wx) * (1.f - wy); w01a = wx * (1.f - wy);
    w10a = (1.f - wx) * wy;         w11a = wx * wy;
    off0 = ((s * 3 + 0) * (RES_ * RES_) + yi * RES_ + xi) * C_;
  }
  {
    float fx = (px + 1.f) * 0.5f * 127.f, fy = (pz + 1.f) * 0.5f * 127.f;
    int xi = min((int)fx, RES_ - 2), yi = min((int)fy, RES_ - 2);
    float wx = fx - (float)xi, wy = fy - (float)yi;
    w00b = (1.f - wx) * (1.f - wy); w01b = wx * (1.f - wy);
    w10b = (1.f - wx) * wy;         w11b = wx * wy;
    off1 = ((s * 3 + 1) * (RES_ * RES_) + yi * RES_ + xi) * C_;
  }
  {
    float fx = (py + 1.f) * 0.5f * 127.f, fy = (pz + 1.f) * 0.5f * 127.f;
    int xi = min((int)fx, RES_ - 2), yi = min((int)fy, RES_ - 2);
    float wx = fx - (float)xi, wy = fy - (float)yi;
    w00c = (1.f - wx) * (1.f - wy); w01c = wx * (1.f - wy);
    w10c = (1.f - wx) * wy;         w11c = wx * wy;
    off2 = ((s * 3 + 2) * (RES_ * RES_) + yi * RES_ + xi) * C_;
  }

  // ---- gather: channels [48q,48q+48) as 6 chunks of 8; f32x2 packed math,
  //      bf16 repack via v_perm truncation (RTZ) ----
#pragma unroll
  for (int u = 0; u < 6; ++u) {
    const int f = 48 * q + 8 * u;  // chunk never crosses a plane boundary
    const int pl = f >> 5;
    const int c = f & 31;
    const int off = (pl == 0) ? off0 : ((pl == 1) ? off1 : off2);
    const float W00 = (pl == 0) ? w00a : ((pl == 1) ? w00b : w00c);
    const float W01 = (pl == 0) ? w01a : ((pl == 1) ? w01b : w01c);
    const float W10 = (pl == 0) ? w10a : ((pl == 1) ? w10b : w10c);
    const float W11 = (pl == 0) ? w11a : ((pl == 1) ? w11b : w11c);
    const unsigned short* bp = codeT + off + c;
    const uint4 A = *(const uint4*)(bp);
    const uint4 B = *(const uint4*)(bp + C_);
    const uint4 Cv = *(const uint4*)(bp + RES_ * C_);
    const uint4 D = *(const uint4*)(bp + RES_ * C_ + C_);
    const unsigned int aw[4] = {A.x, A.y, A.z, A.w};
    const unsigned int bw[4] = {B.x, B.y, B.z, B.w};
    const unsigned int cw[4] = {Cv.x, Cv.y, Cv.z, Cv.w};
    const unsigned int dw[4] = {D.x, D.y, D.z, D.w};
    const f32x2 W00v = {W00, W00}, W01v = {W01, W01}, W10v = {W10, W10}, W11v = {W11, W11};
    unsigned int ow[4];
#pragma unroll
    for (int e2 = 0; e2 < 4; ++e2) {
      const f32x2 va = {__uint_as_float(aw[e2] << 16), __uint_as_float(aw[e2] & 0xffff0000u)};
      const f32x2 vb = {__uint_as_float(bw[e2] << 16), __uint_as_float(bw[e2] & 0xffff0000u)};
      const f32x2 vc = {__uint_as_float(cw[e2] << 16), __uint_as_float(cw[e2] & 0xffff0000u)};
      const f32x2 vd = {__uint_as_float(dw[e2] << 16), __uint_as_float(dw[e2] & 0xffff0000u)};
      const f32x2 fv = W00v * va + W01v * vb + W10v * vc + W11v * vd;
      ow[e2] = __builtin_amdgcn_perm(__float_as_uint(fv[1]), __float_as_uint(fv[0]),
                                     0x07060302u);
    }
    *(uint4*)(fA + p * ROWP + f) = make_uint4(ow[0], ow[1], ow[2], ow[3]);
  }
  // wave-local LDS (wave w: rows [32w,32w+32)) -> no barrier.

  const int rowA = 32 * w + ln;
  const int rowB = rowA + 16;

  // ---- layer 1: feats(128x96) @ W1^T -> h1 bf16; two m-tiles per wave so
  //      every B-fragment is used twice. All 6 A-frags loaded BEFORE any h1
  //      write: fA region then dead -> safe alias. ----
  {
    bf16x8 aA[3], aB[3];
#pragma unroll
    for (int kt = 0; kt < 3; ++kt) {
      aA[kt] = *(const bf16x8*)(fA + rowA * ROWP + kt * 32 + quad * 8);
      aB[kt] = *(const bf16x8*)(fA + rowB * ROWP + kt * 32 + quad * 8);
    }
#pragma unroll
    for (int nt = 0; nt < 8; ++nt) {
      const bf16x8 b0 = *(const bf16x8*)(W1F + ((nt * 3 + 0) * 64 + lane) * 8);
      const bf16x8 b1v = *(const bf16x8*)(W1F + ((nt * 3 + 1) * 64 + lane) * 8);
      const bf16x8 b2v = *(const bf16x8*)(W1F + ((nt * 3 + 2) * 64 + lane) * 8);
      f32x4 accA = {0.f, 0.f, 0.f, 0.f};
      f32x4 accB = {0.f, 0.f, 0.f, 0.f};
      accA = __builtin_amdgcn_mfma_f32_16x16x32_bf16(aA[0], b0, accA, 0, 0, 0);
      accB = __builtin_amdgcn_mfma_f32_16x16x32_bf16(aB[0], b0, accB, 0, 0, 0);
      accA = __builtin_amdgcn_mfma_f32_16x16x32_bf16(aA[1], b1v, accA, 0, 0, 0);
      accB = __builtin_amdgcn_mfma_f32_16x16x32_bf16(aB[1], b1v, accB, 0, 0, 0);
      accA = __builtin_amdgcn_mfma_f32_16x16x32_bf16(aA[2], b2v, accA, 0, 0, 0);
      accB = __builtin_amdgcn_mfma_f32_16x16x32_bf16(aB[2], b2v, accB, 0, 0, 0);
      const int n = nt * 16 + ln;
      const float bias = b1[n];
#pragma unroll
      for (int rr = 0; rr < 4; ++rr) {
        const int mA = 32 * w + quad * 4 + rr;
        const float vA = fmaxf(accA[rr] + bias, 0.f);
        h1s[mA * ROWP + n] = (unsigned short)(__float_as_uint(vA) >> 16);
        const float vB = fmaxf(accB[rr] + bias, 0.f);
        h1s[(mA + 16) * ROWP + n] = (unsigned short)(__float_as_uint(vB) >> 16);
      }
    }
  }

  // ---- layer 2: h1 @ W2^T -> h2 bf16, stored back into the SAME wave-local
  //      rows (h1 dead after the A-frag loads below -> safe alias). ----
  {
    bf16x8 aA[4], aB[4];
#pragma unroll
    for (int kt = 0; kt < 4; ++kt) {
      aA[kt] = *(const bf16x8*)(h1s + rowA * ROWP + kt * 32 + quad * 8);
      aB[kt] = *(const bf16x8*)(h1s + rowB * ROWP + kt * 32 + quad * 8);
    }
#pragma unroll
    for (int nt = 0; nt < 8; ++nt) {
      const bf16x8 b0 = *(const bf16x8*)(W2F + ((nt * 4 + 0) * 64 + lane) * 8);
      const bf16x8 b1v = *(const bf16x8*)(W2F + ((nt * 4 + 1) * 64 + lane) * 8);
      const bf16x8 b2v = *(const bf16x8*)(W2F + ((nt * 4 + 2) * 64 + lane) * 8);
      const bf16x8 b3v = *(const bf16x8*)(W2F + ((nt * 4 + 3) * 64 + lane) * 8);
      f32x4 accA = {0.f, 0.f, 0.f, 0.f};
      f32x4 accB = {0.f, 0.f, 0.f, 0.f};
      accA = __builtin_amdgcn_mfma_f32_16x16x32_bf16(aA[0], b0, accA, 0, 0, 0);
      accB = __builtin_amdgcn_mfma_f32_16x16x32_bf16(aB[0], b0, accB, 0, 0, 0);
      accA = __builtin_amdgcn_mfma_f32_16x16x32_bf16(aA[1], b1v, accA, 0, 0, 0);
      accB = __builtin_amdgcn_mfma_f32_16x16x32_bf16(aB[1], b1v, accB, 0, 0, 0);
      accA = __builtin_amdgcn_mfma_f32_16x16x32_bf16(aA[2], b2v, accA, 0, 0, 0);
      accB = __builtin_amdgcn_mfma_f32_16x16x32_bf16(aB[2], b2v, accB, 0, 0, 0);
      accA = __builtin_amdgcn_mfma_f32_16x16x32_bf16(aA[3], b3v, accA, 0, 0, 0);
      accB = __builtin_amdgcn_mfma_f32_16x16x32_bf16(aB[3], b3v, accB, 0, 0, 0);
      const int n = nt * 16 + ln;
      const float b2n = b2[n];
#pragma unroll
      for (int rr = 0; rr < 4; ++rr) {
        const int mA = 32 * w + quad * 4 + rr;
        const float vA = fmaxf(accA[rr] + b2n, 0.f);
        h1s[mA * ROWP + n] = (unsigned short)(__float_as_uint(vA) >> 16);
        const float vB = fmaxf(accB[rr] + b2n, 0.f);
        h1s[(mA + 16) * ROWP + n] = (unsigned short)(__float_as_uint(vB) >> 16);
      }
    }
  }

  // ---- layer 3 via MFMA: h2(32x128) @ W3F(128x16, cols 0-3 valid) ----
  f32x4 acc3A = {0.f, 0.f, 0.f, 0.f};
  f32x4 acc3B = {0.f, 0.f, 0.f, 0.f};
  {
    bf16x8 aA[4], aB[4];
#pragma unroll
    for (int kt = 0; kt < 4; ++kt) {
      aA[kt] = *(const bf16x8*)(h1s + rowA * ROWP + kt * 32 + quad * 8);
      aB[kt] = *(const bf16x8*)(h1s + rowB * ROWP + kt * 32 + quad * 8);
    }
#pragma unroll
    for (int kt = 0; kt < 4; ++kt) {
      const bf16x8 bk = *(const bf16x8*)(W3F + (kt * 64 + lane) * 8);
      acc3A = __builtin_amdgcn_mfma_f32_16x16x32_bf16(aA[kt], bk, acc3A, 0, 0, 0);
      acc3B = __builtin_amdgcn_mfma_f32_16x16x32_bf16(aB[kt], bk, acc3B, 0, 0, 0);
    }
  }

  // ---- redistribute C[row=quad*4+rr][col] to the old (q_s, rr_s) lane
  //      mapping: lane wants C[quad*4+rr_s][q_s], held by lane quad*16+q_s
  //      in reg rr_s. Static reg index via broadcast+select. ----
  float valA = 0.f, valB = 0.f;
#pragma unroll
  for (int rr = 0; rr < 4; ++rr) {
    const float tA = __shfl(acc3A[rr], (lane & 48) + q_s);
    const float tB = __shfl(acc3B[rr], (lane & 48) + q_s);
    if (rr_s == rr) { valA = tA; valB = tB; }
  }

  // ---- tail: unchanged occ/softplus/sigmoid/store ----
  const float bq = b3[q_s];
  {
    const float val = valA + bq;
    float outv;
    if (q_s == 0) {
      const int occ = (occw0 >> occb0) & 1;
      const float sp = val > 20.f ? val : log1pf(expf(val));
      outv = occ ? sp : 0.f;
    } else {
      outv = 1.f / (1.f + expf(-val));
    }
    sr[(pG0 + m_o0) * 4 + q_s] = outv;
  }
  {
    const float val = valB + bq;
    float outv;
    if (q_s == 0) {
      const int occ = (occw1 >> occb1) & 1;
      const float sp = val > 20.f ? val : log1pf(expf(val));
      outv = occ ? sp : 0.f;
    } else {
      outv = 1.f / (1.f + expf(-val));
    }
    sr[(pG0 + m_o1) * 4 + q_s] = outv;
  }
}

// ---------------------------------------------------------------------------
// K2: volume rendering, one wave per ray
// ---------------------------------------------------------------------------
__global__ __launch_bounds__(256) void k_render(
    const float* __restrict__ rays_o, const float* __restrict__ rays_d,
    const float4* __restrict__ sr4, float* __restrict__ out) {
  const int lane = threadIdx.x & 63;
  const int ray = blockIdx.x * 4 + (threadIdx.x >> 6);
  const int s = ray >> 11, r = ray & (R_ - 1);
  const float* ob = rays_o + (s * R_ + r) * 3;
  const float* db = rays_d + (s * R_ + r) * 3;
  float nearv, farv;
  near_far(ob[0], ob[1], ob[2], db[0], db[1], db[2], nearv, farv);
  const float delta = (farv - nearv) * (1.0f / K_);

  const int k0 = lane * 2;
  const float4 A = sr4[ray * K_ + k0];
  const float4 B = sr4[ray * K_ + k0 + 1];
  const float tau0 = A.x * delta, tau1 = B.x * delta;
  const float local = tau0 + tau1;
  float scan = local;
#pragma unroll
  for (int off = 1; off < 64; off <<= 1) {
    const float vsh = __shfl_up(scan, off);
    if (lane >= off) scan += vsh;
  }
  const float pre = scan - local;
  const float T0 = expf(-pre);
  const float T1 = expf(-(pre + tau0));
  const float a0 = 1.f - expf(-tau0);
  const float a1 = 1.f - expf(-tau1);
  const float w0 = (T0 > 1e-4f) ? a0 * T0 : 0.f;
  const float w1 = (T1 > 1e-4f) ? a1 * T1 : 0.f;
  const float z0 = nearv + (farv - nearv) * ((k0 + 0.5f) * (1.f / K_));
  const float z1 = nearv + (farv - nearv) * ((k0 + 1.5f) * (1.f / K_));

  float sw = w0 + w1;
  float sd = w0 * z0 + w1 * z1;
  float sred = w0 * A.y + w1 * B.y;
  float sgrn = w0 * A.z + w1 * B.z;
  float sblu = w0 * A.w + w1 * B.w;
#pragma unroll
  for (int mk = 32; mk >= 1; mk >>= 1) {
    sw += __shfl_xor(sw, mk);
    sd += __shfl_xor(sd, mk);
    sred += __shfl_xor(sred, mk);
    sgrn += __shfl_xor(sgrn, mk);
    sblu += __shfl_xor(sblu, mk);
  }
  if (lane == 0) {
    out[ray] = sw;
    out[S_ * R_ + ray] = sd;
    out[2 * S_ * R_ + ray * 3 + 0] = sred;
    out[2 * S_ * R_ + ray * 3 + 1] = sgrn;
    out[2 * S_ * R_ + ray * 3 + 2] = sblu;
  }
}

// ---------------------------------------------------------------------------
extern "C" void kernel_launch(void* const* d_in, const int* in_sizes, int n_in,
                              void* d_out, int out_size, void* d_ws, size_t ws_size,
                              hipStream_t stream) {
  const float* rays_o = (const float*)d_in[0];
  const float* rays_d = (const float*)d_in[1];
  const float* code = (const float*)d_in[2];
  const int* dgrid = (const int*)d_in[3];
  const float* W1 = (const float*)d_in[5];
  const float* b1 = (const float*)d_in[6];
  const float* W2 = (const float*)d_in[7];
  const float* b2 = (const float*)d_in[8];
  const float* W3 = (const float*)d_in[9];
  const float* b3 = (const float*)d_in[10];

  float* ws = (float*)d_ws;
  unsigned short* codeT = (unsigned short*)(ws + CODET_OFF);
  unsigned short* W1F = (unsigned short*)(ws + W1F_OFF);
  unsigned short* W2F = (unsigned short*)(ws + W2F_OFF);
  unsigned int* gbits = (unsigned int*)(ws + GB_OFF);
  unsigned short* W3F = (unsigned short*)(ws + W3F_OFF);
  float* sr = ws + SR_OFF;

  hipLaunchKernelGGL(k_pre, dim3(1808), dim3(256), 0, stream,
                     code, codeT, dgrid, gbits, W1, W2, W3, W1F, W2F, W3F);
  hipLaunchKernelGGL(k_fused, dim3(S_ * R_), dim3(256), 0, stream,
                     rays_o, rays_d, codeT, gbits, W1F, b1, W2F, b2, W3F, b3, sr);
  hipLaunchKernelGGL(k_render, dim3((S_ * R_) / 4), dim3(256), 0, stream,
                     rays_o, rays_d, (const float4*)sr, (float*)d_out);
}

// Round 10
// 276.502 us; speedup vs baseline: 1.0228x; 1.0086x over previous
//
#include <hip/hip_runtime.h>
#include <math.h>

#define S_ 4
#define R_ 2048
#define K_ 128
#define C_ 32
#define RES_ 128
#define G_ 128
#define H_ 128

typedef __bf16 bf16x8 __attribute__((ext_vector_type(8)));
typedef float f32x4 __attribute__((ext_vector_type(4)));
typedef float f32x2 __attribute__((ext_vector_type(2)));
typedef unsigned short u16x8 __attribute__((ext_vector_type(8)));

// ws layout (in floats)
#define CODET_OFF 0
#define CODET_SZ  (S_*3*RES_*RES_*C_/2)   // bf16: 3145728 floats
#define W1F_OFF   (CODET_OFF + CODET_SZ)
#define W1F_SZ    (128*96/2)              // 6144 floats
#define W2F_OFF   (W1F_OFF + W1F_SZ)
#define W2F_SZ    (128*128/2)             // 8192 floats
#define GB_OFF    (W2F_OFF + W2F_SZ)
#define GB_SZ     (S_*G_*G_*G_/32)        // 262144 uint words
#define W3F_OFF   (GB_OFF + GB_SZ)
#define W3F_SZ    (4*64*8/2)              // 1024 floats (2048 bf16)
#define SR_OFF    (W3F_OFF + W3F_SZ)      // 4194304 floats

// Unified LDS row stride (bf16 elements). 272 B row stride: 16B-multiple
// (aligned b128), consecutive rows offset by 4 banks -> worst 2-way = free.
// Frozen-regime notes (R2-R4,R6): launch-bound changes, LDS swizzle, packed
// f32x2 partials, fused-render tail all regressed (spill/race). R9 landed
// layer-3-via-MFMA (172.7 us, VALU 56->46%). R10 changes ONLY the gather:
// depth-2 software pipeline (issue chunk u+1's corner loads before chunk
// u's compute) — the 6 serial load rounds were the largest exposed-latency
// block. VGPR headroom 64->~96 under the (256,4) cap of 128.
#define ROWP 136

__device__ __forceinline__ unsigned short f2bf(float x) {
  unsigned int u = __float_as_uint(x);
  unsigned int r = u + 0x7fffu + ((u >> 16) & 1u);
  return (unsigned short)(r >> 16);
}

// ---------------------------------------------------------------------------
// K0 (merged pre-pass):
//   blocks 0..767    : transpose+cvt code -> (S,3,RES,RES,C) bf16 (float4 loads)
//   blocks 768..1791 : density bitmask (coalesced loads + wave ballot)
//   blocks 1792..1807: weight fragments (W1F/W2F/W3F) in MFMA B-operand order
// ---------------------------------------------------------------------------
__global__ __launch_bounds__(256) void k_pre(
    const float* __restrict__ src, unsigned short* __restrict__ dst,
    const int* __restrict__ dgrid, unsigned int* __restrict__ gbits,
    const float* __restrict__ W1, const float* __restrict__ W2,
    const float* __restrict__ W3,
    unsigned short* __restrict__ W1F, unsigned short* __restrict__ W2F,
    unsigned short* __restrict__ W3F) {
  __shared__ unsigned int tile[32 * 129];  // 16512 B, bf16-pair packed
  const int t = threadIdx.x;
  const int b = blockIdx.x;
  if (b < 768) {
    const int slab = b >> 6;          // 12 slabs = S*3 planes
    const int xy0 = (b & 63) << 8;    // 256 xy per block
    const float* sp = src + slab * (C_ * RES_ * RES_);
    unsigned short* dp = dst + slab * (RES_ * RES_ * C_);
    const int c = t >> 3, xg = t & 7;
#pragma unroll
    for (int j = 0; j < 8; ++j) {
      const int chunk = xg + 8 * j;  // 64 float4-chunks cover 256 xy
      const float4 v = *(const float4*)(sp + c * (RES_ * RES_) + xy0 + chunk * 4);
      const unsigned int lo = (unsigned int)f2bf(v.x) | ((unsigned int)f2bf(v.y) << 16);
      const unsigned int hi = (unsigned int)f2bf(v.z) | ((unsigned int)f2bf(v.w) << 16);
      tile[c * 129 + chunk * 2] = lo;
      tile[c * 129 + chunk * 2 + 1] = hi;
    }
    __syncthreads();
    const int xyb = t >> 2, chunk4 = t & 3;
#pragma unroll
    for (int j = 0; j < 4; ++j) {
      const int xy = 64 * j + xyb;
      const int idx = xy >> 1, sh = (xy & 1) * 16;
      u16x8 pk;
#pragma unroll
      for (int cc = 0; cc < 8; ++cc)
        pk[cc] = (unsigned short)(tile[(chunk4 * 8 + cc) * 129 + idx] >> sh);
      *(u16x8*)(dp + (xy0 + xy) * C_ + chunk4 * 8) = pk;
    }
  } else if (b < 1792) {
    const int base0 = (b - 768) * 8192;
    const int lane = t & 63;
#pragma unroll 4
    for (int j = 0; j < 32; ++j) {
      const int idx = base0 + j * 256 + t;
      const unsigned long long m = __ballot(dgrid[idx] > 0);
      if (lane == 0)
        gbits[idx >> 5] = (unsigned int)m;
      else if (lane == 32)
        gbits[idx >> 5] = (unsigned int)(m >> 32);
    }
  } else {
    const int slice = b - 1792;  // 0..15
    for (int i = slice * 256 + t; i < 128 * 96; i += 16 * 256) {
      const int j = i & 7, lane = (i >> 3) & 63, fi = i >> 9;
      const int nt = fi / 3, kt = fi - 3 * nt;
      const int k = kt * 32 + (lane >> 4) * 8 + j;
      const int n = nt * 16 + (lane & 15);
      W1F[i] = f2bf(W1[k * H_ + n]);
    }
    for (int i = slice * 256 + t; i < 128 * 128; i += 16 * 256) {
      const int j = i & 7, lane = (i >> 3) & 63, fi = i >> 9;
      const int nt = fi >> 2, kt = fi & 3;
      const int k = kt * 32 + (lane >> 4) * 8 + j;
      const int n = nt * 16 + (lane & 15);
      W2F[i] = f2bf(W2[k * H_ + n]);
    }
    // W3F: 4 k-frags of (128 x 4->16-padded); slices 0..7 cover i<2048.
    // Address clamped to n&3 (always in-bounds, max W3[511]); value selected
    // to 0 for n>=4. No OOB even under speculative load transforms.
    for (int i = slice * 256 + t; i < 4 * 64 * 8; i += 16 * 256) {
      const int j = i & 7, lane = (i >> 3) & 63, kt = i >> 9;
      const int k = kt * 32 + (lane >> 4) * 8 + j;
      const int n = lane & 15;
      const unsigned short v = f2bf(W3[k * 4 + (n & 3)]);
      W3F[i] = (n < 4) ? v : (unsigned short)0;
    }
  }
}

// ---------------------------------------------------------------------------
__device__ __forceinline__ void near_far(float ox, float oy, float oz,
                                         float dx, float dy, float dz,
                                         float& nearv, float& farv) {
  float ddx = fabsf(dx) < 1e-9f ? 1e-9f : dx;
  float ddy = fabsf(dy) < 1e-9f ? 1e-9f : dy;
  float ddz = fabsf(dz) < 1e-9f ? 1e-9f : dz;
  float ix = 1.f / ddx, iy = 1.f / ddy, iz = 1.f / ddz;
  float t1x = (-1.f - ox) * ix, t2x = (1.f - ox) * ix;
  float t1y = (-1.f - oy) * iy, t2y = (1.f - oy) * iy;
  float t1z = (-1.f - oz) * iz, t2z = (1.f - oz) * iz;
  float mnx = fminf(t1x, t2x), mxx = fmaxf(t1x, t2x);
  float mny = fminf(t1y, t2y), mxy = fmaxf(t1y, t2y);
  float mnz = fminf(t1z, t2z), mxz = fmaxf(t1z, t2z);
  nearv = fmaxf(fmaxf(fmaxf(mnx, mny), mnz), 0.2f);
  farv = fmaxf(fminf(fminf(mxx, mxy), mxz), nearv);
}

// ---------------------------------------------------------------------------
// K1: fused sampling + MLP.
// Body = R9 (172.7 us, VGPR 64, no spill, layer-3 via MFMA) with ONE change:
// depth-2 pipelined gather. All 6 chunk base addresses precomputed (static
// unroll); chunk u+1's 4 corner loads issue before chunk u's weighting math,
// halving the exposed L2 latency of the 6 serial gather rounds.
// ---------------------------------------------------------------------------
__global__ __launch_bounds__(256, 4) void k_fused(
    const float* __restrict__ rays_o, const float* __restrict__ rays_d,
    const unsigned short* __restrict__ codeT, const unsigned int* __restrict__ gbits,
    const unsigned short* __restrict__ W1F, const float* __restrict__ b1,
    const unsigned short* __restrict__ W2F, const float* __restrict__ b2,
    const unsigned short* __restrict__ W3F, const float* __restrict__ b3,
    float* __restrict__ sr) {
  __shared__ __align__(16) unsigned short smem[128 * ROWP];  // 34816 B (fA & h1 & h2 alias)
  unsigned short* fA = smem;   // feats: rows [p][0..96)
  unsigned short* h1s = smem;  // h1 then h2: rows [m][0..128)

  const int t = threadIdx.x;
  const int w = t >> 6, lane = t & 63;
  const int quad = lane >> 4, ln = lane & 15;
  const int p = t >> 1, q = t & 1;  // sampling role: point p (0..127), channel-half q
  const int ray = blockIdx.x;       // 8192 rays, one per block
  const int s = ray >> 11;
  const int pG0 = ray * K_;

  const float* ob = rays_o + ray * 3;
  const float* db = rays_d + ray * 3;
  const float ox = ob[0], oy = ob[1], oz = ob[2];
  const float dx = db[0], dy = db[1], dz = db[2];
  float nearv, farv;
  near_far(ox, oy, oz, dx, dy, dz, nearv, farv);

  // ---- EARLY occupancy-grid loads for this lane's two epilogue points ----
  const int q_s = ln & 3, rr_s = ln >> 2;
  const int m_o0 = 32 * w + quad * 4 + rr_s;
  const int m_o1 = m_o0 + 16;
  unsigned int occw0, occw1;
  int occb0, occb1;
  {
    const float zm = nearv + (farv - nearv) * ((m_o0 + 0.5f) * (1.0f / K_));
    const float pxm = fminf(fmaxf(ox + dx * zm, -1.f), 1.f);
    const float pym = fminf(fmaxf(oy + dy * zm, -1.f), 1.f);
    const float pzm = fminf(fmaxf(oz + dz * zm, -1.f), 1.f);
    const int i0 = min((int)((pxm + 1.f) * 64.f), G_ - 1);
    const int i1 = min((int)((pym + 1.f) * 64.f), G_ - 1);
    const int i2 = min((int)((pzm + 1.f) * 64.f), G_ - 1);
    const int bidx = ((s * G_ + i0) * G_ + i1) * G_ + i2;
    occw0 = gbits[bidx >> 5];
    occb0 = bidx & 31;
  }
  {
    const float zm = nearv + (farv - nearv) * ((m_o1 + 0.5f) * (1.0f / K_));
    const float pxm = fminf(fmaxf(ox + dx * zm, -1.f), 1.f);
    const float pym = fminf(fmaxf(oy + dy * zm, -1.f), 1.f);
    const float pzm = fminf(fmaxf(oz + dz * zm, -1.f), 1.f);
    const int i0 = min((int)((pxm + 1.f) * 64.f), G_ - 1);
    const int i1 = min((int)((pym + 1.f) * 64.f), G_ - 1);
    const int i2 = min((int)((pzm + 1.f) * 64.f), G_ - 1);
    const int bidx = ((s * G_ + i0) * G_ + i1) * G_ + i2;
    occw1 = gbits[bidx >> 5];
    occb1 = bidx & 31;
  }

  // ---- this thread's sample point ----
  const float zs = nearv + (farv - nearv) * ((p + 0.5f) * (1.0f / K_));
  const float px = fminf(fmaxf(ox + dx * zs, -1.f), 1.f);
  const float py = fminf(fmaxf(oy + dy * zs, -1.f), 1.f);
  const float pz = fminf(fmaxf(oz + dz * zs, -1.f), 1.f);

  // ---- per-plane bilinear setup ----
  float w00a, w01a, w10a, w11a, w00b, w01b, w10b, w11b, w00c, w01c, w10c, w11c;
  int off0, off1, off2;
  {
    float fx = (px + 1.f) * 0.5f * 127.f, fy = (py + 1.f) * 0.5f * 127.f;
    int xi = min((int)fx, RES_ - 2), yi = min((int)fy, RES_ - 2);
    float wx = fx - (float)xi, wy = fy - (float)yi;
    w00a = (1.f - wx) * (1.f - wy); w01a = wx * (1.f - wy);
    w10a = (1.f - wx) * wy;         w11a = wx * wy;
    off0 = ((s * 3 + 0) * (RES_ * RES_) + yi * RES_ + xi) * C_;
  }
  {
    float fx = (px + 1.f) * 0.5f * 127.f, fy = (pz + 1.f) * 0.5f * 127.f;
    int xi = min((int)fx, RES_ - 2), yi = min((int)fy, RES_ - 2);
    float wx = fx - (float)xi, wy = fy - (float)yi;
    w00b = (1.f - wx) * (1.f - wy); w01b = wx * (1.f - wy);
    w10b = (1.f - wx) * wy;         w11b = wx * wy;
    off1 = ((s * 3 + 1) * (RES_ * RES_) + yi * RES_ + xi) * C_;
  }
  {
    float fx = (py + 1.f) * 0.5f * 127.f, fy = (pz + 1.f) * 0.5f * 127.f;
    int xi = min((int)fx, RES_ - 2), yi = min((int)fy, RES_ - 2);
    float wx = fx - (float)xi, wy = fy - (float)yi;
    w00c = (1.f - wx) * (1.f - wy); w01c = wx * (1.f - wy);
    w10c = (1.f - wx) * wy;         w11c = wx * wy;
    off2 = ((s * 3 + 2) * (RES_ * RES_) + yi * RES_ + xi) * C_;
  }

  // ---- gather, depth-2 pipeline: chunk base addresses precomputed (static
  //      indices only); chunk u+1's corner loads issue before chunk u's
  //      weighting. f32x2 packed math, bf16 repack via v_perm RTZ. ----
  const unsigned short* bps[6];
#pragma unroll
  for (int u = 0; u < 6; ++u) {
    const int f = 48 * q + 8 * u;  // chunk never crosses a plane boundary
    const int pl = f >> 5;
    const int off = (pl == 0) ? off0 : ((pl == 1) ? off1 : off2);
    bps[u] = codeT + off + (f & 31);
  }
  uint4 A0 = *(const uint4*)(bps[0]);
  uint4 B0 = *(const uint4*)(bps[0] + C_);
  uint4 Cv0 = *(const uint4*)(bps[0] + RES_ * C_);
  uint4 D0 = *(const uint4*)(bps[0] + RES_ * C_ + C_);
#pragma unroll
  for (int u = 0; u < 6; ++u) {
    uint4 A1, B1, Cv1, D1;
    if (u < 5) {
      const unsigned short* bp = bps[u + 1];
      A1 = *(const uint4*)(bp);
      B1 = *(const uint4*)(bp + C_);
      Cv1 = *(const uint4*)(bp + RES_ * C_);
      D1 = *(const uint4*)(bp + RES_ * C_ + C_);
    }
    const int f = 48 * q + 8 * u;
    const int pl = f >> 5;
    const float W00 = (pl == 0) ? w00a : ((pl == 1) ? w00b : w00c);
    const float W01 = (pl == 0) ? w01a : ((pl == 1) ? w01b : w01c);
    const float W10 = (pl == 0) ? w10a : ((pl == 1) ? w10b : w10c);
    const float W11 = (pl == 0) ? w11a : ((pl == 1) ? w11b : w11c);
    const unsigned int aw[4] = {A0.x, A0.y, A0.z, A0.w};
    const unsigned int bw[4] = {B0.x, B0.y, B0.z, B0.w};
    const unsigned int cw[4] = {Cv0.x, Cv0.y, Cv0.z, Cv0.w};
    const unsigned int dw[4] = {D0.x, D0.y, D0.z, D0.w};
    const f32x2 W00v = {W00, W00}, W01v = {W01, W01}, W10v = {W10, W10}, W11v = {W11, W11};
    unsigned int ow[4];
#pragma unroll
    for (int e2 = 0; e2 < 4; ++e2) {
      const f32x2 va = {__uint_as_float(aw[e2] << 16), __uint_as_float(aw[e2] & 0xffff0000u)};
      const f32x2 vb = {__uint_as_float(bw[e2] << 16), __uint_as_float(bw[e2] & 0xffff0000u)};
      const f32x2 vc = {__uint_as_float(cw[e2] << 16), __uint_as_float(cw[e2] & 0xffff0000u)};
      const f32x2 vd = {__uint_as_float(dw[e2] << 16), __uint_as_float(dw[e2] & 0xffff0000u)};
      const f32x2 fv = W00v * va + W01v * vb + W10v * vc + W11v * vd;
      ow[e2] = __builtin_amdgcn_perm(__float_as_uint(fv[1]), __float_as_uint(fv[0]),
                                     0x07060302u);
    }
    *(uint4*)(fA + p * ROWP + f) = make_uint4(ow[0], ow[1], ow[2], ow[3]);
    if (u < 5) { A0 = A1; B0 = B1; Cv0 = Cv1; D0 = D1; }
  }
  // wave-local LDS (wave w: rows [32w,32w+32)) -> no barrier.

  const int rowA = 32 * w + ln;
  const int rowB = rowA + 16;

  // ---- layer 1: feats(128x96) @ W1^T -> h1 bf16; two m-tiles per wave so
  //      every B-fragment is used twice. All 6 A-frags loaded BEFORE any h1
  //      write: fA region then dead -> safe alias. ----
  {
    bf16x8 aA[3], aB[3];
#pragma unroll
    for (int kt = 0; kt < 3; ++kt) {
      aA[kt] = *(const bf16x8*)(fA + rowA * ROWP + kt * 32 + quad * 8);
      aB[kt] = *(const bf16x8*)(fA + rowB * ROWP + kt * 32 + quad * 8);
    }
#pragma unroll
    for (int nt = 0; nt < 8; ++nt) {
      const bf16x8 b0 = *(const bf16x8*)(W1F + ((nt * 3 + 0) * 64 + lane) * 8);
      const bf16x8 b1v = *(const bf16x8*)(W1F + ((nt * 3 + 1) * 64 + lane) * 8);
      const bf16x8 b2v = *(const bf16x8*)(W1F + ((nt * 3 + 2) * 64 + lane) * 8);
      f32x4 accA = {0.f, 0.f, 0.f, 0.f};
      f32x4 accB = {0.f, 0.f, 0.f, 0.f};
      accA = __builtin_amdgcn_mfma_f32_16x16x32_bf16(aA[0], b0, accA, 0, 0, 0);
      accB = __builtin_amdgcn_mfma_f32_16x16x32_bf16(aB[0], b0, accB, 0, 0, 0);
      accA = __builtin_amdgcn_mfma_f32_16x16x32_bf16(aA[1], b1v, accA, 0, 0, 0);
      accB = __builtin_amdgcn_mfma_f32_16x16x32_bf16(aB[1], b1v, accB, 0, 0, 0);
      accA = __builtin_amdgcn_mfma_f32_16x16x32_bf16(aA[2], b2v, accA, 0, 0, 0);
      accB = __builtin_amdgcn_mfma_f32_16x16x32_bf16(aB[2], b2v, accB, 0, 0, 0);
      const int n = nt * 16 + ln;
      const float bias = b1[n];
#pragma unroll
      for (int rr = 0; rr < 4; ++rr) {
        const int mA = 32 * w + quad * 4 + rr;
        const float vA = fmaxf(accA[rr] + bias, 0.f);
        h1s[mA * ROWP + n] = (unsigned short)(__float_as_uint(vA) >> 16);
        const float vB = fmaxf(accB[rr] + bias, 0.f);
        h1s[(mA + 16) * ROWP + n] = (unsigned short)(__float_as_uint(vB) >> 16);
      }
    }
  }

  // ---- layer 2: h1 @ W2^T -> h2 bf16, stored back into the SAME wave-local
  //      rows (h1 dead after the A-frag loads below -> safe alias). ----
  {
    bf16x8 aA[4], aB[4];
#pragma unroll
    for (int kt = 0; kt < 4; ++kt) {
      aA[kt] = *(const bf16x8*)(h1s + rowA * ROWP + kt * 32 + quad * 8);
      aB[kt] = *(const bf16x8*)(h1s + rowB * ROWP + kt * 32 + quad * 8);
    }
#pragma unroll
    for (int nt = 0; nt < 8; ++nt) {
      const bf16x8 b0 = *(const bf16x8*)(W2F + ((nt * 4 + 0) * 64 + lane) * 8);
      const bf16x8 b1v = *(const bf16x8*)(W2F + ((nt * 4 + 1) * 64 + lane) * 8);
      const bf16x8 b2v = *(const bf16x8*)(W2F + ((nt * 4 + 2) * 64 + lane) * 8);
      const bf16x8 b3v = *(const bf16x8*)(W2F + ((nt * 4 + 3) * 64 + lane) * 8);
      f32x4 accA = {0.f, 0.f, 0.f, 0.f};
      f32x4 accB = {0.f, 0.f, 0.f, 0.f};
      accA = __builtin_amdgcn_mfma_f32_16x16x32_bf16(aA[0], b0, accA, 0, 0, 0);
      accB = __builtin_amdgcn_mfma_f32_16x16x32_bf16(aB[0], b0, accB, 0, 0, 0);
      accA = __builtin_amdgcn_mfma_f32_16x16x32_bf16(aA[1], b1v, accA, 0, 0, 0);
      accB = __builtin_amdgcn_mfma_f32_16x16x32_bf16(aB[1], b1v, accB, 0, 0, 0);
      accA = __builtin_amdgcn_mfma_f32_16x16x32_bf16(aA[2], b2v, accA, 0, 0, 0);
      accB = __builtin_amdgcn_mfma_f32_16x16x32_bf16(aB[2], b2v, accB, 0, 0, 0);
      accA = __builtin_amdgcn_mfma_f32_16x16x32_bf16(aA[3], b3v, accA, 0, 0, 0);
      accB = __builtin_amdgcn_mfma_f32_16x16x32_bf16(aB[3], b3v, accB, 0, 0, 0);
      const int n = nt * 16 + ln;
      const float b2n = b2[n];
#pragma unroll
      for (int rr = 0; rr < 4; ++rr) {
        const int mA = 32 * w + quad * 4 + rr;
        const float vA = fmaxf(accA[rr] + b2n, 0.f);
        h1s[mA * ROWP + n] = (unsigned short)(__float_as_uint(vA) >> 16);
        const float vB = fmaxf(accB[rr] + b2n, 0.f);
        h1s[(mA + 16) * ROWP + n] = (unsigned short)(__float_as_uint(vB) >> 16);
      }
    }
  }

  // ---- layer 3 via MFMA: h2(32x128) @ W3F(128x16, cols 0-3 valid) ----
  f32x4 acc3A = {0.f, 0.f, 0.f, 0.f};
  f32x4 acc3B = {0.f, 0.f, 0.f, 0.f};
  {
    bf16x8 aA[4], aB[4];
#pragma unroll
    for (int kt = 0; kt < 4; ++kt) {
      aA[kt] = *(const bf16x8*)(h1s + rowA * ROWP + kt * 32 + quad * 8);
      aB[kt] = *(const bf16x8*)(h1s + rowB * ROWP + kt * 32 + quad * 8);
    }
#pragma unroll
    for (int kt = 0; kt < 4; ++kt) {
      const bf16x8 bk = *(const bf16x8*)(W3F + (kt * 64 + lane) * 8);
      acc3A = __builtin_amdgcn_mfma_f32_16x16x32_bf16(aA[kt], bk, acc3A, 0, 0, 0);
      acc3B = __builtin_amdgcn_mfma_f32_16x16x32_bf16(aB[kt], bk, acc3B, 0, 0, 0);
    }
  }

  // ---- redistribute C[row=quad*4+rr][col] to the old (q_s, rr_s) lane
  //      mapping: lane wants C[quad*4+rr_s][q_s], held by lane quad*16+q_s
  //      in reg rr_s. Static reg index via broadcast+select. ----
  float valA = 0.f, valB = 0.f;
#pragma unroll
  for (int rr = 0; rr < 4; ++rr) {
    const float tA = __shfl(acc3A[rr], (lane & 48) + q_s);
    const float tB = __shfl(acc3B[rr], (lane & 48) + q_s);
    if (rr_s == rr) { valA = tA; valB = tB; }
  }

  // ---- tail: unchanged occ/softplus/sigmoid/store ----
  const float bq = b3[q_s];
  {
    const float val = valA + bq;
    float outv;
    if (q_s == 0) {
      const int occ = (occw0 >> occb0) & 1;
      const float sp = val > 20.f ? val : log1pf(expf(val));
      outv = occ ? sp : 0.f;
    } else {
      outv = 1.f / (1.f + expf(-val));
    }
    sr[(pG0 + m_o0) * 4 + q_s] = outv;
  }
  {
    const float val = valB + bq;
    float outv;
    if (q_s == 0) {
      const int occ = (occw1 >> occb1) & 1;
      const float sp = val > 20.f ? val : log1pf(expf(val));
      outv = occ ? sp : 0.f;
    } else {
      outv = 1.f / (1.f + expf(-val));
    }
    sr[(pG0 + m_o1) * 4 + q_s] = outv;
  }
}

// ---------------------------------------------------------------------------
// K2: volume rendering, one wave per ray
// ---------------------------------------------------------------------------
__global__ __launch_bounds__(256) void k_render(
    const float* __restrict__ rays_o, const float* __restrict__ rays_d,
    const float4* __restrict__ sr4, float* __restrict__ out) {
  const int lane = threadIdx.x & 63;
  const int ray = blockIdx.x * 4 + (threadIdx.x >> 6);
  const int s = ray >> 11, r = ray & (R_ - 1);
  const float* ob = rays_o + (s * R_ + r) * 3;
  const float* db = rays_d + (s * R_ + r) * 3;
  float nearv, farv;
  near_far(ob[0], ob[1], ob[2], db[0], db[1], db[2], nearv, farv);
  const float delta = (farv - nearv) * (1.0f / K_);

  const int k0 = lane * 2;
  const float4 A = sr4[ray * K_ + k0];
  const float4 B = sr4[ray * K_ + k0 + 1];
  const float tau0 = A.x * delta, tau1 = B.x * delta;
  const float local = tau0 + tau1;
  float scan = local;
#pragma unroll
  for (int off = 1; off < 64; off <<= 1) {
    const float vsh = __shfl_up(scan, off);
    if (lane >= off) scan += vsh;
  }
  const float pre = scan - local;
  const float T0 = expf(-pre);
  const float T1 = expf(-(pre + tau0));
  const float a0 = 1.f - expf(-tau0);
  const float a1 = 1.f - expf(-tau1);
  const float w0 = (T0 > 1e-4f) ? a0 * T0 : 0.f;
  const float w1 = (T1 > 1e-4f) ? a1 * T1 : 0.f;
  const float z0 = nearv + (farv - nearv) * ((k0 + 0.5f) * (1.f / K_));
  const float z1 = nearv + (farv - nearv) * ((k0 + 1.5f) * (1.f / K_));

  float sw = w0 + w1;
  float sd = w0 * z0 + w1 * z1;
  float sred = w0 * A.y + w1 * B.y;
  float sgrn = w0 * A.z + w1 * B.z;
  float sblu = w0 * A.w + w1 * B.w;
#pragma unroll
  for (int mk = 32; mk >= 1; mk >>= 1) {
    sw += __shfl_xor(sw, mk);
    sd += __shfl_xor(sd, mk);
    sred += __shfl_xor(sred, mk);
    sgrn += __shfl_xor(sgrn, mk);
    sblu += __shfl_xor(sblu, mk);
  }
  if (lane == 0) {
    out[ray] = sw;
    out[S_ * R_ + ray] = sd;
    out[2 * S_ * R_ + ray * 3 + 0] = sred;
    out[2 * S_ * R_ + ray * 3 + 1] = sgrn;
    out[2 * S_ * R_ + ray * 3 + 2] = sblu;
  }
}

// ---------------------------------------------------------------------------
extern "C" void kernel_launch(void* const* d_in, const int* in_sizes, int n_in,
                              void* d_out, int out_size, void* d_ws, size_t ws_size,
                              hipStream_t stream) {
  const float* rays_o = (const float*)d_in[0];
  const float* rays_d = (const float*)d_in[1];
  const float* code = (const float*)d_in[2];
  const int* dgrid = (const int*)d_in[3];
  const float* W1 = (const float*)d_in[5];
  const float* b1 = (const float*)d_in[6];
  const float* W2 = (const float*)d_in[7];
  const float* b2 = (const float*)d_in[8];
  const float* W3 = (const float*)d_in[9];
  const float* b3 = (const float*)d_in[10];

  float* ws = (float*)d_ws;
  unsigned short* codeT = (unsigned short*)(ws + CODET_OFF);
  unsigned short* W1F = (unsigned short*)(ws + W1F_OFF);
  unsigned short* W2F = (unsigned short*)(ws + W2F_OFF);
  unsigned int* gbits = (unsigned int*)(ws + GB_OFF);
  unsigned short* W3F = (unsigned short*)(ws + W3F_OFF);
  float* sr = ws + SR_OFF;

  hipLaunchKernelGGL(k_pre, dim3(1808), dim3(256), 0, stream,
                     code, codeT, dgrid, gbits, W1, W2, W3, W1F, W2F, W3F);
  hipLaunchKernelGGL(k_fused, dim3(S_ * R_), dim3(256), 0, stream,
                     rays_o, rays_d, codeT, gbits, W1F, b1, W2F, b2, W3F, b3, sr);
  hipLaunchKernelGGL(k_render, dim3((S_ * R_) / 4), dim3(256), 0, stream,
                     rays_o, rays_d, (const float4*)sr, (float*)d_out);
}